// Round 6
// baseline (117.132 us; speedup 1.0000x reference)
//
#include <hip/hip_runtime.h>

// Problem constants (from reference)
#define NITEMS 100000
#define NRATE  5
#define BB     4096
#define LL     200
#define DD     64
#define NTILES 6250   // 6250*16 = 100000 exactly
#define NWAVES 2048   // 512 blocks * 4 waves

typedef short short8  __attribute__((ext_vector_type(8)));
typedef float f32x4   __attribute__((ext_vector_type(4)));
typedef float f32x2   __attribute__((ext_vector_type(2)));
typedef int   i32x4   __attribute__((ext_vector_type(4)));
typedef int   i32x2   __attribute__((ext_vector_type(2)));

// RTNA (round-half-away) fp32->bf16: bits+0x8000, take top 16. Max err 0.5 ulp.
static __device__ __forceinline__ short f2bf(float f) {
  return (short)((__builtin_bit_cast(unsigned, f) + 0x8000u) >> 16);
}
// pack two fp32 -> dword {lo=bf16(a), hi=bf16(b)} : 2 adds + 1 v_perm_b32
static __device__ __forceinline__ unsigned pk2bf(float a, float b) {
  const unsigned ua = __builtin_bit_cast(unsigned, a) + 0x8000u;
  const unsigned ub = __builtin_bit_cast(unsigned, b) + 0x8000u;
  return __builtin_amdgcn_perm(ub, ua, 0x07060302u);
}
// k-space permutation: storage position q holds h-component pi(q)=(q&3)*16+(q>>2).
// Applied consistently to pre_uv, r5p, w2p rows -> all MFMA dots unchanged.
static __device__ __forceinline__ int kperm(int p) {
  return ((p & 3) << 4) | (p >> 2);
}

// ---------------------------------------------------------------------------
// k_pre: blocks 0..511: grid-stride over 6250 16-item tiles (2048 waves,
//   waves 0..105 do 4 tiles, rest 3; exact coverage, no bounds checks).
//   pre_uv[item][q=n*4+nt] = bf16(v2e[item] . w1a_row[nt*16+n])
// block 512: w2p[o*64+q] = bf16(w2W[o][pi(q)]);
//            r5p[r*64+q] = w1b[pi(q)] + r2e[r] . w1b_row[pi(q)]   (fp32)
// ---------------------------------------------------------------------------
__global__ __launch_bounds__(256) void k_pre(
    const float* __restrict__ v2e, const float* __restrict__ r2e,
    const float* __restrict__ w1W, const float* __restrict__ w1b,
    const float* __restrict__ w2W,
    short* __restrict__ pre_uv, short* __restrict__ w2p,
    float* __restrict__ r5p)
{
  const int tid = threadIdx.x;
  const int blk = blockIdx.x;

  if (blk >= 512) {
    for (int idx = tid; idx < 64 * 64; idx += 256) {
      const int o = idx >> 6, p = idx & 63;
      w2p[idx] = f2bf(w2W[o * 64 + kperm(p)]);
    }
    for (int idx = tid; idx < NRATE * 64; idx += 256) {
      const int r = idx >> 6, p = idx & 63;
      const int o = kperm(p);
      const float4* wr = reinterpret_cast<const float4*>(w1W + o * 128 + 64);
      const float4* rr = reinterpret_cast<const float4*>(r2e + r * 64);
      float s = w1b[o];
#pragma unroll
      for (int q = 0; q < 16; ++q) {
        const float4 a = wr[q], b = rr[q];
        s += a.x * b.x + a.y * b.y + a.z * b.z + a.w * b.w;
      }
      r5p[r * 64 + p] = s;
    }
    return;
  }

  const int wave = tid >> 6, lane = tid & 63;
  const int n = lane & 15, quad = lane >> 4;
  const int gw = blk * 4 + wave;                 // 0..2047
  const int ntile = (gw < (NTILES - 3 * NWAVES)) ? 4 : 3;   // 106 waves do 4

  // B fragment (amortized over ntile MFMA passes): B[k][o], k=kh*32+quad*8+j
  short8 bfr[2][4];
#pragma unroll
  for (int nt = 0; nt < 4; ++nt)
#pragma unroll
    for (int kh = 0; kh < 2; ++kh) {
      const float4* p = reinterpret_cast<const float4*>(
          w1W + (nt * 16 + n) * 128 + kh * 32 + quad * 8);
      const float4 x0 = p[0], x1 = p[1];
      i32x4 pk = {(int)pk2bf(x0.x, x0.y), (int)pk2bf(x0.z, x0.w),
                  (int)pk2bf(x1.x, x1.y), (int)pk2bf(x1.z, x1.w)};
      bfr[kh][nt] = __builtin_bit_cast(short8, pk);
    }

  // software-pipelined grid-stride tile loop
  int tile = gw;
  float4 cur0, cur1, cur2, cur3;
  {
    const size_t row = (size_t)(tile * 16 + n);
    const float4* p = reinterpret_cast<const float4*>(v2e + row * 64 + quad * 8);
    cur0 = p[0]; cur1 = p[1];
    const float4* q = reinterpret_cast<const float4*>(v2e + row * 64 + 32 + quad * 8);
    cur2 = q[0]; cur3 = q[1];
  }

  for (int it = 0; it < ntile; ++it) {
    const int next = tile + NWAVES;
    float4 nx0, nx1, nx2, nx3;
    if (it + 1 < ntile) {
      const size_t row = (size_t)(next * 16 + n);
      const float4* p = reinterpret_cast<const float4*>(v2e + row * 64 + quad * 8);
      nx0 = p[0]; nx1 = p[1];
      const float4* q = reinterpret_cast<const float4*>(v2e + row * 64 + 32 + quad * 8);
      nx2 = q[0]; nx3 = q[1];
    }

    short8 afr[2];
    {
      i32x4 pk0 = {(int)pk2bf(cur0.x, cur0.y), (int)pk2bf(cur0.z, cur0.w),
                   (int)pk2bf(cur1.x, cur1.y), (int)pk2bf(cur1.z, cur1.w)};
      afr[0] = __builtin_bit_cast(short8, pk0);
      i32x4 pk1 = {(int)pk2bf(cur2.x, cur2.y), (int)pk2bf(cur2.z, cur2.w),
                   (int)pk2bf(cur3.x, cur3.y), (int)pk2bf(cur3.z, cur3.w)};
      afr[1] = __builtin_bit_cast(short8, pk1);
    }

    f32x4 d[4];
#pragma unroll
    for (int nt = 0; nt < 4; ++nt) {
      f32x4 z = {0.f, 0.f, 0.f, 0.f};
      z = __builtin_amdgcn_mfma_f32_16x16x32_bf16(afr[0], bfr[0][nt], z, 0, 0, 0);
      z = __builtin_amdgcn_mfma_f32_16x16x32_bf16(afr[1], bfr[1][nt], z, 0, 0, 0);
      d[nt] = z;
    }

    // C/D: lane (n,quad), reg (nt,r) = row quad*4+r, col nt*16+n.
    // kperm store: cols {nt*16+n} -> positions n*4+nt, one 8B store per r.
    const int ib = tile * 16;
#pragma unroll
    for (int r = 0; r < 4; ++r) {
      const int item = ib + quad * 4 + r;
      i32x2 s = {(int)pk2bf(d[0][r], d[1][r]), (int)pk2bf(d[2][r], d[3][r])};
      *reinterpret_cast<i32x2*>(pre_uv + (size_t)item * 64 + n * 4) = s;
    }

    tile = next;
    cur0 = nx0; cur1 = nx1; cur2 = nx2; cur3 = nx3;
  }
}

// ---------------------------------------------------------------------------
// k_main: wave-per-b (1024 blocks x 4 waves), __launch_bounds__(256,3) for
// >=12 waves/CU (gather-latency-bound: in-flight bytes is the knob).
// ALL 26 pre_uv gathers issued before compute. Per-wave private r5 LDS copy
// -> ZERO barriers. Bias folded into MFMA C-init (free). Tail tile 12
// masked by 0/1 multiplier.
// ---------------------------------------------------------------------------
__global__ __launch_bounds__(256, 3) void k_main(
    const short* __restrict__ pre_uv, const float* __restrict__ r5p,
    const short* __restrict__ w2p, const float* __restrict__ w2b,
    const int* __restrict__ huv, const int* __restrict__ hrr,
    float* __restrict__ out)
{
  __shared__ __align__(16) float s_r5[4][5 * 68];   // per-wave copy, no barrier

  const int tid  = threadIdx.x;
  const int wave = tid >> 6, lane = tid & 63;
  const int n = lane & 15, quad = lane >> 4;
  const int b = blockIdx.x * 4 + wave;

  // wave-private r5 copy (5*64 = 320, 5 iters of 64 lanes)
#pragma unroll
  for (int i = 0; i < 5; ++i) {
    const int idx = i * 64 + lane;
    s_r5[wave][(idx >> 6) * 68 + (idx & 63)] = r5p[idx];
  }

  const int* hu = huv + b * LL;
  const int* hr = hrr + b * LL;

  // tile t covers rows l = t*16 + n. Tail tile 12: l = 192..199.
  int iv[13], ir[13];
#pragma unroll
  for (int t = 0; t < 12; ++t) {
    iv[t] = hu[t * 16 + n];
    ir[t] = hr[t * 16 + n];
  }
  {
    const int lc = min(192 + n, LL - 1);
    iv[12] = hu[lc];
    ir[12] = hr[lc];
  }

  // issue ALL pre_uv gathers (26 independent 16B loads in flight per wave)
  short8 u[13][2];
#pragma unroll
  for (int t = 0; t < 13; ++t)
#pragma unroll
    for (int kh = 0; kh < 2; ++kh)
      u[t][kh] = *reinterpret_cast<const short8*>(
          pre_uv + (size_t)iv[t] * 64 + kh * 32 + quad * 8);

  // B fragments for W2 (permuted k-space): B[q][o] = w2p[o*64+q]
  short8 bfr[2][4];
#pragma unroll
  for (int nt = 0; nt < 4; ++nt)
#pragma unroll
    for (int kh = 0; kh < 2; ++kh)
      bfr[kh][nt] = *reinterpret_cast<const short8*>(
          w2p + (nt * 16 + n) * 64 + kh * 32 + quad * 8);

  // bias folded into MFMA C-init: every C row gets +bias once per tile
  f32x4 zb[4];
#pragma unroll
  for (int nt = 0; nt < 4; ++nt) {
    const float bv = w2b[nt * 16 + n];
    zb[nt] = f32x4{bv, bv, bv, bv};
  }

  const float tailm = (quad < 2) ? 1.0f : 0.0f;  // tile-12 valid rows: m<8
  f32x2 acc2[4] = {{0.f, 0.f}, {0.f, 0.f}, {0.f, 0.f}, {0.f, 0.f}};

#pragma unroll
  for (int t = 0; t < 13; ++t) {
    short8 afr[2];
#pragma unroll
    for (int kh = 0; kh < 2; ++kh) {
      const i32x4 up = __builtin_bit_cast(i32x4, u[t][kh]);
      const f32x2* rp = reinterpret_cast<const f32x2*>(
          &s_r5[wave][ir[t] * 68 + kh * 32 + quad * 8]);
      i32x4 hpk;
#pragma unroll
      for (int j = 0; j < 4; ++j) {
        const unsigned p = (unsigned)up[j];
        f32x2 uf = {__builtin_bit_cast(float, p << 16),
                    __builtin_bit_cast(float, p & 0xffff0000u)};
        const f32x2 s = uf + rp[j];
        hpk[j] = (int)pk2bf(fmaxf(s.x, 0.f), fmaxf(s.y, 0.f));
      }
      afr[kh] = __builtin_bit_cast(short8, hpk);
    }

    f32x4 d[4];
#pragma unroll
    for (int nt = 0; nt < 4; ++nt) {
      f32x4 z = zb[nt];
      z = __builtin_amdgcn_mfma_f32_16x16x32_bf16(afr[0], bfr[0][nt], z, 0, 0, 0);
      z = __builtin_amdgcn_mfma_f32_16x16x32_bf16(afr[1], bfr[1][nt], z, 0, 0, 0);
      d[nt] = z;
    }

#pragma unroll
    for (int nt = 0; nt < 4; ++nt) {
      const float m0 = fmaxf(d[nt][0], 0.f), m1 = fmaxf(d[nt][1], 0.f);
      const float m2 = fmaxf(d[nt][2], 0.f), m3 = fmaxf(d[nt][3], 0.f);
      f32x2 s = {m0 + m1, m2 + m3};
      if (t == 12) { s.x *= tailm; s.y *= tailm; }
      acc2[nt] += s;
    }
  }

  // collapse pairs, sum across the 4 quads -> every lane has all 4 sums
  float acc[4];
#pragma unroll
  for (int nt = 0; nt < 4; ++nt) {
    float v = acc2[nt].x + acc2[nt].y;
    v += __shfl_xor(v, 16, 64);
    v += __shfl_xor(v, 32, 64);
    acc[nt] = v;
  }

  // coalesced: lane (n,quad) stores column quad*16+n (one dword per lane)
  out[b * 64 + quad * 16 + n] = acc[quad] * (1.0f / (float)LL);
}

// ---------------------------------------------------------------------------
// Fallback (no workspace): all-fp32, one block per b, weights in padded LDS.
// ---------------------------------------------------------------------------
__global__ __launch_bounds__(256) void k_fallback(
    const float* __restrict__ v2e, const float* __restrict__ r2e,
    const float* __restrict__ w1W, const float* __restrict__ w1b,
    const float* __restrict__ w2W, const float* __restrict__ w2b,
    const int* __restrict__ huv, const int* __restrict__ hrr,
    float* __restrict__ out)
{
  __shared__ float sw1[64][129];
  __shared__ float sw2[64][65];
  __shared__ float sx[4][128];
  __shared__ float sh[4][64];
  __shared__ float red[4][64];

  const int tid = threadIdx.x;
  const int wave = tid >> 6, lane = tid & 63;
  const int b = blockIdx.x;

  for (int idx = tid; idx < 64 * 128; idx += 256) sw1[idx >> 7][idx & 127] = w1W[idx];
  for (int idx = tid; idx < 64 * 64; idx += 256) sw2[idx >> 6][idx & 63] = w2W[idx];
  __syncthreads();

  const float b1o = w1b[lane], b2o = w2b[lane];
  float acc = 0.f;

  for (int l = wave; l < LL; l += 4) {
    const int iv = huv[b * LL + l];
    const int ir = hrr[b * LL + l];
    sx[wave][lane]      = v2e[iv * 64 + lane];
    sx[wave][64 + lane] = r2e[ir * 64 + lane];
    __syncthreads();
    float h = b1o;
    for (int i = 0; i < 128; ++i) h += sx[wave][i] * sw1[lane][i];
    sh[wave][lane] = fmaxf(h, 0.f);
    __syncthreads();
    float o = b2o;
    for (int i = 0; i < 64; ++i) o += sh[wave][i] * sw2[lane][i];
    acc += fmaxf(o, 0.f);
  }

  red[wave][lane] = acc;
  __syncthreads();
  if (tid < 64) {
    const float s = red[0][tid] + red[1][tid] + red[2][tid] + red[3][tid];
    out[b * 64 + tid] = s * (1.0f / (float)LL);
  }
}

extern "C" void kernel_launch(void* const* d_in, const int* in_sizes, int n_in,
                              void* d_out, int out_size, void* d_ws, size_t ws_size,
                              hipStream_t stream) {
  (void)in_sizes; (void)n_in; (void)out_size;
  const float* v2e = (const float*)d_in[0];   // [100000,64]
  const float* r2e = (const float*)d_in[1];   // [5,64]
  const float* w1W = (const float*)d_in[2];   // [64,128]
  const float* w1b = (const float*)d_in[3];   // [64]
  const float* w2W = (const float*)d_in[4];   // [64,64]
  const float* w2b = (const float*)d_in[5];   // [64]
  // d_in[6] = nodes (unused by uv=True branch)
  const int* huv = (const int*)d_in[7];       // [4096,200]
  const int* hrr = (const int*)d_in[8];       // [4096,200]
  float* out = (float*)d_out;                 // [4096,64]

  const size_t OFF_R5 = (size_t)NITEMS * 64 * sizeof(short);   // 12,800,000
  const size_t OFF_W2 = OFF_R5 + NRATE * 64 * sizeof(float);   // +1,280
  const size_t NEED   = OFF_W2 + 64 * 64 * sizeof(short);      // +8,192

  if (ws_size >= NEED) {
    short* pre_uv = (short*)d_ws;
    float* r5p    = (float*)((char*)d_ws + OFF_R5);
    short* w2p    = (short*)((char*)d_ws + OFF_W2);

    k_pre<<<513, 256, 0, stream>>>(v2e, r2e, w1W, w1b, w2W, pre_uv, w2p, r5p);
    k_main<<<BB / 4, 256, 0, stream>>>(pre_uv, r5p, w2p, w2b, huv, hrr, out);
  } else {
    k_fallback<<<BB, 256, 0, stream>>>(v2e, r2e, w1W, w1b, w2W, w2b, huv, hrr, out);
  }
}

// Round 7
// 113.972 us; speedup vs baseline: 1.0277x; 1.0277x over previous
//
#include <hip/hip_runtime.h>

// Problem constants (from reference)
#define NITEMS 100000
#define NRATE  5
#define BB     4096
#define LL     200
#define DD     64
#define NTILES 6250   // 6250*16 = 100000 exactly
#define NWAVES 2048   // 512 blocks * 4 waves

typedef short short8  __attribute__((ext_vector_type(8)));
typedef float f32x4   __attribute__((ext_vector_type(4)));
typedef float f32x2   __attribute__((ext_vector_type(2)));
typedef int   i32x4   __attribute__((ext_vector_type(4)));
typedef int   i32x2   __attribute__((ext_vector_type(2)));

// RTNA (round-half-away) fp32->bf16: bits+0x8000, take top 16. Max err 0.5 ulp.
static __device__ __forceinline__ short f2bf(float f) {
  return (short)((__builtin_bit_cast(unsigned, f) + 0x8000u) >> 16);
}
// pack two fp32 -> dword {lo=bf16(a), hi=bf16(b)} : 2 adds + 1 v_perm_b32
static __device__ __forceinline__ unsigned pk2bf(float a, float b) {
  const unsigned ua = __builtin_bit_cast(unsigned, a) + 0x8000u;
  const unsigned ub = __builtin_bit_cast(unsigned, b) + 0x8000u;
  return __builtin_amdgcn_perm(ub, ua, 0x07060302u);
}
// k-space permutation: storage position p holds h-component pi(p)=(p&3)*16+(p>>2).
// Applied consistently to pre_uv, r5p, w2p rows -> all MFMA dots unchanged.
static __device__ __forceinline__ int kperm(int p) {
  return ((p & 3) << 4) | (p >> 2);
}

// ---------------------------------------------------------------------------
// k_pre: blocks 0..511: grid-stride over 6250 16-item tiles.
//   pre8[item] : 64 B of e4m3 fp8. Byte q = quad*16 + kh*8 + j holds
//   permuted-k position p = kh*32 + quad*8 + j, i.e. orig dim pi(p).
//   => k_main lane (n,quad) gets its full 16-value fragment from ONE 16-B
//   load at offset quad*16, matching w2p/r5p fragment index math.
// block 512: w2p[o*64+p] = bf16(w2W[o][pi(p)]);
//            r5p[r*64+p] = w1b[pi(p)] + r2e[r] . w1b_row[pi(p)]   (fp32)
// ---------------------------------------------------------------------------
__global__ __launch_bounds__(256) void k_pre(
    const float* __restrict__ v2e, const float* __restrict__ r2e,
    const float* __restrict__ w1W, const float* __restrict__ w1b,
    const float* __restrict__ w2W,
    unsigned char* __restrict__ pre8, short* __restrict__ w2p,
    float* __restrict__ r5p)
{
  const int tid = threadIdx.x;
  const int blk = blockIdx.x;

  if (blk >= 512) {
    for (int idx = tid; idx < 64 * 64; idx += 256) {
      const int o = idx >> 6, p = idx & 63;
      w2p[idx] = f2bf(w2W[o * 64 + kperm(p)]);
    }
    for (int idx = tid; idx < NRATE * 64; idx += 256) {
      const int r = idx >> 6, p = idx & 63;
      const int o = kperm(p);
      const float4* wr = reinterpret_cast<const float4*>(w1W + o * 128 + 64);
      const float4* rr = reinterpret_cast<const float4*>(r2e + r * 64);
      float s = w1b[o];
#pragma unroll
      for (int q = 0; q < 16; ++q) {
        const float4 a = wr[q], b = rr[q];
        s += a.x * b.x + a.y * b.y + a.z * b.z + a.w * b.w;
      }
      r5p[r * 64 + p] = s;
    }
    return;
  }

  const int wave = tid >> 6, lane = tid & 63;
  const int n = lane & 15, quad = lane >> 4;
  const int gw = blk * 4 + wave;                 // 0..2047
  const int ntile = (gw < (NTILES - 3 * NWAVES)) ? 4 : 3;   // 106 waves do 4

  // Lane (n,quad) produces orig dims o = nt*16+n -> perm pos p = 4n+nt ->
  // byte q0+nt with q0 = ((n>>1)&3)*16 + (n>>3)*8 + (n&1)*4 (one dword).
  const int q0 = ((n >> 1) & 3) * 16 + (n >> 3) * 8 + (n & 1) * 4;

  // B fragment (amortized over ntile MFMA passes): B[k][o], k=kh*32+quad*8+j
  short8 bfr[2][4];
#pragma unroll
  for (int nt = 0; nt < 4; ++nt)
#pragma unroll
    for (int kh = 0; kh < 2; ++kh) {
      const float4* p = reinterpret_cast<const float4*>(
          w1W + (nt * 16 + n) * 128 + kh * 32 + quad * 8);
      const float4 x0 = p[0], x1 = p[1];
      i32x4 pk = {(int)pk2bf(x0.x, x0.y), (int)pk2bf(x0.z, x0.w),
                  (int)pk2bf(x1.x, x1.y), (int)pk2bf(x1.z, x1.w)};
      bfr[kh][nt] = __builtin_bit_cast(short8, pk);
    }

  // software-pipelined grid-stride tile loop
  int tile = gw;
  float4 cur0, cur1, cur2, cur3;
  {
    const size_t row = (size_t)(tile * 16 + n);
    const float4* p = reinterpret_cast<const float4*>(v2e + row * 64 + quad * 8);
    cur0 = p[0]; cur1 = p[1];
    const float4* q = reinterpret_cast<const float4*>(v2e + row * 64 + 32 + quad * 8);
    cur2 = q[0]; cur3 = q[1];
  }

  for (int it = 0; it < ntile; ++it) {
    const int next = tile + NWAVES;
    float4 nx0, nx1, nx2, nx3;
    if (it + 1 < ntile) {
      const size_t row = (size_t)(next * 16 + n);
      const float4* p = reinterpret_cast<const float4*>(v2e + row * 64 + quad * 8);
      nx0 = p[0]; nx1 = p[1];
      const float4* q = reinterpret_cast<const float4*>(v2e + row * 64 + 32 + quad * 8);
      nx2 = q[0]; nx3 = q[1];
    }

    short8 afr[2];
    {
      i32x4 pk0 = {(int)pk2bf(cur0.x, cur0.y), (int)pk2bf(cur0.z, cur0.w),
                   (int)pk2bf(cur1.x, cur1.y), (int)pk2bf(cur1.z, cur1.w)};
      afr[0] = __builtin_bit_cast(short8, pk0);
      i32x4 pk1 = {(int)pk2bf(cur2.x, cur2.y), (int)pk2bf(cur2.z, cur2.w),
                   (int)pk2bf(cur3.x, cur3.y), (int)pk2bf(cur3.z, cur3.w)};
      afr[1] = __builtin_bit_cast(short8, pk1);
    }

    f32x4 d[4];
#pragma unroll
    for (int nt = 0; nt < 4; ++nt) {
      f32x4 z = {0.f, 0.f, 0.f, 0.f};
      z = __builtin_amdgcn_mfma_f32_16x16x32_bf16(afr[0], bfr[0][nt], z, 0, 0, 0);
      z = __builtin_amdgcn_mfma_f32_16x16x32_bf16(afr[1], bfr[1][nt], z, 0, 0, 0);
      d[nt] = z;
    }

    // C/D: lane (n,quad), reg (nt,r) = item quad*4+r (of tile), dim nt*16+n.
    // Pack 4 dims -> one fp8 dword at byte q0 (RNE pack, saturating).
    const int ib = tile * 16;
#pragma unroll
    for (int r = 0; r < 4; ++r) {
      const int item = ib + quad * 4 + r;
      int pkd = 0;
      pkd = __builtin_amdgcn_cvt_pk_fp8_f32(d[0][r], d[1][r], pkd, false);
      pkd = __builtin_amdgcn_cvt_pk_fp8_f32(d[2][r], d[3][r], pkd, true);
      *reinterpret_cast<int*>(pre8 + (size_t)item * 64 + q0) = pkd;
    }

    tile = next;
    cur0 = nx0; cur1 = nx1; cur2 = nx2; cur3 = nx3;
  }
}

// ---------------------------------------------------------------------------
// k_main: wave-per-b (1024 blocks x 4 waves). 13 l-tiles per wave; ALL 13
// 16-B fp8 gathers issued before compute. fp8->f32 via v_cvt_pk_f32_fp8,
// + r5 (fp32, LDS, wave-private copy -> no barrier), relu, pack bf16,
// layer-2 bf16 MFMA with bias folded into C-init. Tail tile 12 masked.
// ---------------------------------------------------------------------------
__global__ __launch_bounds__(256) void k_main(
    const unsigned char* __restrict__ pre8, const float* __restrict__ r5p,
    const short* __restrict__ w2p, const float* __restrict__ w2b,
    const int* __restrict__ huv, const int* __restrict__ hrr,
    float* __restrict__ out)
{
  __shared__ __align__(16) float s_r5[4][5 * 68];   // per-wave copy, no barrier

  const int tid  = threadIdx.x;
  const int wave = tid >> 6, lane = tid & 63;
  const int n = lane & 15, quad = lane >> 4;
  const int b = blockIdx.x * 4 + wave;

  // wave-private r5 copy (5*64 = 320, 5 iters of 64 lanes)
#pragma unroll
  for (int i = 0; i < 5; ++i) {
    const int idx = i * 64 + lane;
    s_r5[wave][(idx >> 6) * 68 + (idx & 63)] = r5p[idx];
  }

  const int* hu = huv + b * LL;
  const int* hr = hrr + b * LL;

  // tile t covers rows l = t*16 + n. Tail tile 12: l = 192..199.
  int iv[13], ir[13];
#pragma unroll
  for (int t = 0; t < 12; ++t) {
    iv[t] = hu[t * 16 + n];
    ir[t] = hr[t * 16 + n];
  }
  {
    const int lc = min(192 + n, LL - 1);
    iv[12] = hu[lc];
    ir[12] = hr[lc];
  }

  // issue ALL fp8 gathers (13 independent 16-B loads in flight per wave);
  // lane (n,quad) takes bytes [quad*16, quad*16+16) of item row iv[t].
  i32x4 g[13];
#pragma unroll
  for (int t = 0; t < 13; ++t)
    g[t] = *reinterpret_cast<const i32x4*>(
        pre8 + (size_t)iv[t] * 64 + quad * 16);

  // B fragments for W2 (permuted k-space): B[p][o] = w2p[o*64+p]
  short8 bfr[2][4];
#pragma unroll
  for (int nt = 0; nt < 4; ++nt)
#pragma unroll
    for (int kh = 0; kh < 2; ++kh)
      bfr[kh][nt] = *reinterpret_cast<const short8*>(
          w2p + (nt * 16 + n) * 64 + kh * 32 + quad * 8);

  // bias folded into MFMA C-init
  f32x4 zb[4];
#pragma unroll
  for (int nt = 0; nt < 4; ++nt) {
    const float bv = w2b[nt * 16 + n];
    zb[nt] = f32x4{bv, bv, bv, bv};
  }

  const float tailm = (quad < 2) ? 1.0f : 0.0f;  // tile-12 valid rows: m<8
  f32x2 acc2[4] = {{0.f, 0.f}, {0.f, 0.f}, {0.f, 0.f}, {0.f, 0.f}};

#pragma unroll
  for (int t = 0; t < 13; ++t) {
    const float* rbase = &s_r5[wave][ir[t] * 68 + quad * 8];
    short8 afr[2];
    // kh = 0: dwords g[t][0..1], r5 at +0
    {
      const f32x2* rp = reinterpret_cast<const f32x2*>(rbase);
      f32x2 p0 = __builtin_amdgcn_cvt_pk_f32_fp8(g[t][0], false) + rp[0];
      f32x2 p1 = __builtin_amdgcn_cvt_pk_f32_fp8(g[t][0], true)  + rp[1];
      f32x2 p2 = __builtin_amdgcn_cvt_pk_f32_fp8(g[t][1], false) + rp[2];
      f32x2 p3 = __builtin_amdgcn_cvt_pk_f32_fp8(g[t][1], true)  + rp[3];
      i32x4 hpk = {
        (int)pk2bf(fmaxf(p0.x, 0.f), fmaxf(p0.y, 0.f)),
        (int)pk2bf(fmaxf(p1.x, 0.f), fmaxf(p1.y, 0.f)),
        (int)pk2bf(fmaxf(p2.x, 0.f), fmaxf(p2.y, 0.f)),
        (int)pk2bf(fmaxf(p3.x, 0.f), fmaxf(p3.y, 0.f))};
      afr[0] = __builtin_bit_cast(short8, hpk);
    }
    // kh = 1: dwords g[t][2..3], r5 at +32
    {
      const f32x2* rp = reinterpret_cast<const f32x2*>(rbase + 32);
      f32x2 p0 = __builtin_amdgcn_cvt_pk_f32_fp8(g[t][2], false) + rp[0];
      f32x2 p1 = __builtin_amdgcn_cvt_pk_f32_fp8(g[t][2], true)  + rp[1];
      f32x2 p2 = __builtin_amdgcn_cvt_pk_f32_fp8(g[t][3], false) + rp[2];
      f32x2 p3 = __builtin_amdgcn_cvt_pk_f32_fp8(g[t][3], true)  + rp[3];
      i32x4 hpk = {
        (int)pk2bf(fmaxf(p0.x, 0.f), fmaxf(p0.y, 0.f)),
        (int)pk2bf(fmaxf(p1.x, 0.f), fmaxf(p1.y, 0.f)),
        (int)pk2bf(fmaxf(p2.x, 0.f), fmaxf(p2.y, 0.f)),
        (int)pk2bf(fmaxf(p3.x, 0.f), fmaxf(p3.y, 0.f))};
      afr[1] = __builtin_bit_cast(short8, hpk);
    }

    f32x4 d[4];
#pragma unroll
    for (int nt = 0; nt < 4; ++nt) {
      f32x4 z = zb[nt];
      z = __builtin_amdgcn_mfma_f32_16x16x32_bf16(afr[0], bfr[0][nt], z, 0, 0, 0);
      z = __builtin_amdgcn_mfma_f32_16x16x32_bf16(afr[1], bfr[1][nt], z, 0, 0, 0);
      d[nt] = z;
    }

#pragma unroll
    for (int nt = 0; nt < 4; ++nt) {
      const float m0 = fmaxf(d[nt][0], 0.f), m1 = fmaxf(d[nt][1], 0.f);
      const float m2 = fmaxf(d[nt][2], 0.f), m3 = fmaxf(d[nt][3], 0.f);
      f32x2 s = {m0 + m1, m2 + m3};
      if (t == 12) { s.x *= tailm; s.y *= tailm; }
      acc2[nt] += s;
    }
  }

  // collapse pairs, sum across the 4 quads -> every lane has all 4 sums
  float acc[4];
#pragma unroll
  for (int nt = 0; nt < 4; ++nt) {
    float v = acc2[nt].x + acc2[nt].y;
    v += __shfl_xor(v, 16, 64);
    v += __shfl_xor(v, 32, 64);
    acc[nt] = v;
  }

  // coalesced: lane (n,quad) stores column quad*16+n (one dword per lane)
  out[b * 64 + quad * 16 + n] = acc[quad] * (1.0f / (float)LL);
}

// ---------------------------------------------------------------------------
// Fallback (no workspace): all-fp32, one block per b, weights in padded LDS.
// ---------------------------------------------------------------------------
__global__ __launch_bounds__(256) void k_fallback(
    const float* __restrict__ v2e, const float* __restrict__ r2e,
    const float* __restrict__ w1W, const float* __restrict__ w1b,
    const float* __restrict__ w2W, const float* __restrict__ w2b,
    const int* __restrict__ huv, const int* __restrict__ hrr,
    float* __restrict__ out)
{
  __shared__ float sw1[64][129];
  __shared__ float sw2[64][65];
  __shared__ float sx[4][128];
  __shared__ float sh[4][64];
  __shared__ float red[4][64];

  const int tid = threadIdx.x;
  const int wave = tid >> 6, lane = tid & 63;
  const int b = blockIdx.x;

  for (int idx = tid; idx < 64 * 128; idx += 256) sw1[idx >> 7][idx & 127] = w1W[idx];
  for (int idx = tid; idx < 64 * 64; idx += 256) sw2[idx >> 6][idx & 63] = w2W[idx];
  __syncthreads();

  const float b1o = w1b[lane], b2o = w2b[lane];
  float acc = 0.f;

  for (int l = wave; l < LL; l += 4) {
    const int iv = huv[b * LL + l];
    const int ir = hrr[b * LL + l];
    sx[wave][lane]      = v2e[iv * 64 + lane];
    sx[wave][64 + lane] = r2e[ir * 64 + lane];
    __syncthreads();
    float h = b1o;
    for (int i = 0; i < 128; ++i) h += sx[wave][i] * sw1[lane][i];
    sh[wave][lane] = fmaxf(h, 0.f);
    __syncthreads();
    float o = b2o;
    for (int i = 0; i < 64; ++i) o += sh[wave][i] * sw2[lane][i];
    acc += fmaxf(o, 0.f);
  }

  red[wave][lane] = acc;
  __syncthreads();
  if (tid < 64) {
    const float s = red[0][tid] + red[1][tid] + red[2][tid] + red[3][tid];
    out[b * 64 + tid] = s * (1.0f / (float)LL);
  }
}

extern "C" void kernel_launch(void* const* d_in, const int* in_sizes, int n_in,
                              void* d_out, int out_size, void* d_ws, size_t ws_size,
                              hipStream_t stream) {
  (void)in_sizes; (void)n_in; (void)out_size;
  const float* v2e = (const float*)d_in[0];   // [100000,64]
  const float* r2e = (const float*)d_in[1];   // [5,64]
  const float* w1W = (const float*)d_in[2];   // [64,128]
  const float* w1b = (const float*)d_in[3];   // [64]
  const float* w2W = (const float*)d_in[4];   // [64,64]
  const float* w2b = (const float*)d_in[5];   // [64]
  // d_in[6] = nodes (unused by uv=True branch)
  const int* huv = (const int*)d_in[7];       // [4096,200]
  const int* hrr = (const int*)d_in[8];       // [4096,200]
  float* out = (float*)d_out;                 // [4096,64]

  const size_t OFF_R5 = (size_t)NITEMS * 64;                   // 6,400,000 (fp8 table)
  const size_t OFF_W2 = OFF_R5 + NRATE * 64 * sizeof(float);   // +1,280
  const size_t NEED   = OFF_W2 + 64 * 64 * sizeof(short);      // +8,192

  if (ws_size >= NEED) {
    unsigned char* pre8 = (unsigned char*)d_ws;
    float* r5p = (float*)((char*)d_ws + OFF_R5);
    short* w2p = (short*)((char*)d_ws + OFF_W2);

    k_pre<<<513, 256, 0, stream>>>(v2e, r2e, w1W, w1b, w2W, pre8, w2p, r5p);
    k_main<<<BB / 4, 256, 0, stream>>>(pre8, r5p, w2p, w2b, huv, hrr, out);
  } else {
    k_fallback<<<BB, 256, 0, stream>>>(v2e, r2e, w1W, w1b, w2W, w2b, huv, hrr, out);
  }
}